// Round 18
// baseline (87.141 us; speedup 1.0000x reference)
//
#include <hip/hip_runtime.h>

#define NB 64
#define ZDIM 128
#define NCOEF 1025
#define NFR 128
#define COLS 131200          /* NCOEF*NFR */
#define WINSZ 2048
#define HALFW 1024
#define NSAMP 131072
#define IMPN 4096
#define NCHUNK 16            /* chunks of 8 spans */
#define NCK 15               /* checkpoints after frames 6,14,...,118 */

// workspace layout in floats
#define TF_OFF   0
#define TF_SZ    (NB*COLS)
#define TFT_OFF  (TF_OFF + TF_SZ)
#define TFT_SZ   (NB*NFR*NCOEF)
#define CUR_OFF  (TFT_OFF + TFT_SZ)
#define CUR_SZ   (NB*4*NCOEF*2)
#define CK_OFF   (CUR_OFF + CUR_SZ)
#define CK_SZ    (NCK*NB*NCOEF*2)
#define WINT_OFF (CK_OFF + CK_SZ)
#define WINT_SZ  (WINSZ)
#define TW_OFF   (WINT_OFF + WINT_SZ)
#define TW_SZ    (HALFW*2)
#define ZBF_OFF  (TW_OFF + TW_SZ)
#define ZBF_SZ   (NB*ZDIM/2)

// 2-bit XOR swizzle for the FFT plane: bits[3:2] ^= bits[5:4]
#define PHI(p) ((p) ^ ((((p) >> 4) & 3) << 2))

typedef short bf16x8 __attribute__((ext_vector_type(8)));
typedef float f32x4 __attribute__((ext_vector_type(4)));
typedef float f32x2 __attribute__((ext_vector_type(2)));

// packed complex multiply: 1 pk_mul + 1 pk_fma (fp-contract)
__device__ __forceinline__ f32x2 cmul2(f32x2 a, f32x2 b) {
  f32x2 t = f32x2{a.x, a.x} * b;
  return f32x2{-a.y, a.y} * f32x2{b.y, b.x} + t;
}
// multiply by -i
__device__ __forceinline__ f32x2 nid(f32x2 d) { return f32x2{d.y, -d.x}; }

// full LDS drain + barrier (cross-wave visibility)
#define WGBAR()                                              \
  do {                                                       \
    asm volatile("s_waitcnt lgkmcnt(0)" ::: "memory");       \
    __builtin_amdgcn_s_barrier();                            \
    asm volatile("" ::: "memory");                           \
  } while (0)

// compiler-only fence for wave-local stage boundaries (validated round 17)
#define PIPEFENCE() asm volatile("" ::: "memory")

__device__ __forceinline__ short f2bf(float f) {
  unsigned u = __builtin_bit_cast(unsigned, f);
  u += 0x7FFFu + ((u >> 16) & 1u);      // RNE
  return (short)(u >> 16);
}

__device__ __forceinline__ void gload_lds16(const float* g, float* l) {
  __builtin_amdgcn_global_load_lds(
      (const __attribute__((address_space(1))) unsigned int*)(const void*)g,
      (__attribute__((address_space(3))) unsigned int*)(void*)l, 16, 0, 0);
}

// ---------------------------------------------------------------- init tables (+ z->bf16)
__global__ __launch_bounds__(256) void init_tables(const float* __restrict__ z,
                                                   float* __restrict__ winT,
                                                   float2* __restrict__ twG,
                                                   short* __restrict__ zbf) {
  int i = blockIdx.x * 256 + threadIdx.x;   // grid 32*256 = 8192
  if (i < WINSZ) {
    winT[i] = 0.5f - 0.5f * cosf((float)(2.0 * 3.14159265358979323846 / 2048.0) * (float)i);
  }
  if (i < HALFW) {
    float ang = (float)(-2.0 * 3.14159265358979323846 / 2048.0) * (float)i;
    float sv, cv;
    sincosf(ang, &sv, &cv);
    twG[i] = make_float2(cv, sv);
  }
  if (i < NB * ZDIM) zbf[i] = f2bf(z[i]);
}

// ---------------------------------------------------------------- MFMA GEMM + squash
__global__ __launch_bounds__(256) void tf_gemm_mfma(const short* __restrict__ zbf,
                                                    const float* __restrict__ W,
                                                    const float* __restrict__ bias,
                                                    float* __restrict__ tf) {
  __shared__ float Wt[128 * 32];   // [k][col], 16 KB
  int tid = threadIdx.x;
  int wave = tid >> 6, lane = tid & 63;
  int colb = blockIdx.x * 32;

#pragma unroll
  for (int it = 0; it < 4; ++it) {
    int ci = tid + it * 256;
    const float* src = W + (size_t)(ci >> 3) * COLS + colb + (ci & 7) * 4;
    gload_lds16(src, &Wt[ci * 4]);
  }

  int lr = lane & 15;
  int lk = (lane >> 4) * 8;
  int lq = (lane >> 4) * 4;

  float bv[2];
#pragma unroll
  for (int n = 0; n < 2; ++n) bv[n] = bias[colb + 16 * n + lr];

  f32x4 acc[2];
#pragma unroll
  for (int n = 0; n < 2; ++n)
    acc[n] = f32x4{bv[n], bv[n], bv[n], bv[n]};

  bf16x8 afr[4];
#pragma unroll
  for (int s = 0; s < 4; ++s)
    afr[s] = *reinterpret_cast<const bf16x8*>(zbf + (16 * wave + lr) * ZDIM + s * 32 + lk);

  __syncthreads();   // stage complete

#pragma unroll
  for (int s = 0; s < 4; ++s) {
    bf16x8 bfr[2];
#pragma unroll
    for (int n = 0; n < 2; ++n) {
      const float* wp = &Wt[(s * 32 + lk) * 32 + 16 * n + lr];
      bfr[n] = bf16x8{f2bf(wp[0 * 32]), f2bf(wp[1 * 32]), f2bf(wp[2 * 32]), f2bf(wp[3 * 32]),
                      f2bf(wp[4 * 32]), f2bf(wp[5 * 32]), f2bf(wp[6 * 32]), f2bf(wp[7 * 32])};
    }
#pragma unroll
    for (int n = 0; n < 2; ++n)
      acc[n] = __builtin_amdgcn_mfma_f32_16x16x32_bf16(afr[s], bfr[n], acc[n], 0, 0, 0);
  }

  const float RESR = (1.0f - 0.02f) * 0.99f;
#pragma unroll
  for (int n = 0; n < 2; ++n) {
    int col = colb + 16 * n + lr;
#pragma unroll
    for (int r = 0; r < 4; ++r) {
      int row = 16 * wave + lq + r;
      float x = acc[n][r];
      float sg = 1.0f / (1.0f + __expf(-x));
      tf[(size_t)row * COLS + col] = 0.02f + sg * RESR;
    }
  }
}

// ---------------------------------------------------------------- fwd 2048 FFT (radix-2)
static __device__ __forceinline__ void wg_fft2048(float* ar, float* ai,
                                                  float* br, float* bi,
                                                  const float2* tw,
                                                  float** outr, float** outi) {
  float *xr = ar, *xi = ai, *yr = br, *yi = bi;
  int m = 1;
  for (int s = 0; s < 11; ++s) {
    __syncthreads();
#pragma unroll
    for (int it = 0; it < 4; ++it) {
      int t = (int)threadIdx.x + it * 256;
      int jm = t & ~(m - 1);
      float x0r = xr[t], x0i = xi[t];
      float x1r = xr[t + 1024], x1i = xi[t + 1024];
      float2 w = tw[jm];
      float sr = x0r + x1r, si = x0i + x1i;
      float dr = x0r - x1r, di = x0i - x1i;
      float pr = dr * w.x - di * w.y;
      float pi = dr * w.y + di * w.x;
      yr[t + jm] = sr;      yi[t + jm] = si;
      yr[t + jm + m] = pr;  yi[t + jm + m] = pi;
    }
    float* t0 = xr; xr = yr; yr = t0;
    float* t1 = xi; xi = yi; yi = t1;
    m <<= 1;
  }
  __syncthreads();
  *outr = xr; *outi = xi;
}

__global__ __launch_bounds__(256) void fwd_fft_kernel(const float* __restrict__ imp,
                                                      const float* __restrict__ winT,
                                                      const float2* __restrict__ twG,
                                                      float2* __restrict__ cur) {
  __shared__ float b0r[WINSZ], b0i[WINSZ], b1r[WINSZ], b1i[WINSZ];
  __shared__ float2 tw[HALFW];
  int wg = blockIdx.x;
  int b = wg >> 2, f = wg & 3;
  int tid = threadIdx.x;

  for (int i = tid; i < HALFW; i += 256) tw[i] = twG[i];
  for (int w = tid; w < WINSZ; w += 256) {
    int s = f * HALFW + w;
    float v = (s < IMPN) ? imp[(size_t)b * IMPN + s] * winT[w] : 0.0f;
    b0r[w] = v;
    b0i[w] = 0.0f;
  }
  float *rr, *ri;
  wg_fft2048(b0r, b0i, b1r, b1i, tw, &rr, &ri);
  for (int k = tid; k < NCOEF; k += 256)
    cur[(size_t)wg * NCOEF + k] = make_float2(rr[k], ri[k]);
}

// ---------------------------------------------------------------- recurrence checkpoints + tf transpose
// Checkpoints after frames 6,14,...,118 (mod-8 schedule, NCK=15).
__global__ __launch_bounds__(256) void recur_ck_t(const float* __restrict__ tf,
                                                  const float2* __restrict__ cur,
                                                  float2* __restrict__ ckp,
                                                  float* __restrict__ tft) {
  int id = blockIdx.x * 256 + threadIdx.x;
  if (id >= NB * NCOEF) return;
  int b = id / NCOEF;
  int k = id - b * NCOEF;

  float g = 3.14159265358979323846f * (float)k / 1024.0f;
  float sg, cg;
  sincosf(g, &sg, &cg);
  bool herm = (k == 0) || (k == HALFW);

  const float4* tf4 = (const float4*)(tf + (size_t)b * COLS + (size_t)k * NFR);
  const float2* curb = cur + (size_t)b * 4 * NCOEF + k;
  float* tftb = tft + (size_t)b * NFR * NCOEF + k;

  float pre = 0.0f, pim = 0.0f;
  for (int f4 = 0; f4 < 32; ++f4) {
    float4 tv = tf4[f4];
    float tfs[4] = {tv.x, tv.y, tv.z, tv.w};
#pragma unroll
    for (int u = 0; u < 4; ++u) {
      int f = 4 * f4 + u;
      tftb[(size_t)f * NCOEF] = tfs[u];       // coalesced transpose write
      if (f < 120) {                           // recurrence needed thru f=118
        float tfv = tfs[u];
        float cr = 0.0f, ci = 0.0f;
        if (f < 4) {
          float2 cv = curb[(size_t)f * NCOEF];
          cr = cv.x; ci = cv.y;
        }
        float ire = herm ? 0.0f : pim;
        float rre = fmaf(pre, cg, ire * sg);
        float rim = -fmaf(pre, sg, ire * cg);
        float sre = (cr + rre) * tfv;
        float sim = (ci + rim) * tfv;
        if ((f & 7) == 6)
          ckp[(size_t)((f - 6) >> 3) * NB * NCOEF + (size_t)b * NCOEF + k] = make_float2(sre, sim);
        pre = sre; pim = sim;
      }
    }
  }
}

// ---------------------------------------------------------------- fused recur + DUAL irfft + OLA
// Chunks of 8 spans (grid 1024 = exactly 4 blocks/CU; 32KB LDS admits 5 -> no
// residency loss). Frames processed in PAIRS through two independent
// register-DIF radix-4 FFTs (PA/QA, PB/QB) -> 2x ILP on every dependent
// LDS/VALU chain; 1 barrier per frame. Warm-up frame (8c-1) = pair with
// inactive B. Sync structure per pair identical to the validated round-17 form.
__global__ __launch_bounds__(256) void fused_resyn(const float* __restrict__ tft,
                                                   const float2* __restrict__ cur,
                                                   const float2* __restrict__ ckp,
                                                   const float* __restrict__ winT,
                                                   const float2* __restrict__ twG,
                                                   float* __restrict__ out) {
  __shared__ f32x2 PA[1024], QA[1024];
  __shared__ f32x2 PB[1024], QB[1024];   // 32 KB total

  int bidx = blockIdx.x;
  int b = bidx >> 4, c = bidx & 15;
  int t = threadIdx.x;

  // ---- recurrence slots: k = t + 256*i (i<4); thread 0 also owns k=1024
  float pre[5], pim[5], cgv[5], sgv[5];
#pragma unroll
  for (int i = 0; i < 5; ++i) {
    if (i == 4) { cgv[4] = -1.0f; sgv[4] = 0.0f; }
    else {
      float2 tv = twG[t + 256 * i];
      cgv[i] = tv.x; sgv[i] = -tv.y;       // cos/sin(pi*k/1024)
    }
    pre[i] = 0.0f; pim[i] = 0.0f;
  }
  if (c > 0) {
    const float2* ck = ckp + ((size_t)(c - 1) * NB + b) * NCOEF;   // state after 8c-2
#pragma unroll
    for (int i = 0; i < 5; ++i) {
      if (i == 4 && t != 0) continue;
      int k = (i == 4) ? 1024 : t + 256 * i;
      float2 v = ck[k];
      pre[i] = v.x; pim[i] = v.y;
    }
  }

  // ---- base twiddles (squares/cubes recomputed per pair, packed)
  float2 tl;
  tl = twG[2 * t];          f32x2 w1a = f32x2{tl.x, tl.y};
  tl = twG[8 * (t & 63)];   f32x2 w2a = f32x2{tl.x, tl.y};
  tl = twG[32 * (t & 15)];  f32x2 w3a = f32x2{tl.x, tl.y};
  tl = twG[128 * (t & 3)];  f32x2 w4a = f32x2{tl.x, tl.y};
  tl = twG[t];              f32x2 twp0 = f32x2{tl.x, tl.y};

  // ---- extract constants (digit-reversed positions); 1/2048 scale folded in
  const float Cs = 0.5f / 1024.0f;
  int mb = (t >> 6) + ((t >> 4) & 3) * 4 + ((t >> 2) & 3) * 16 + (t & 3) * 64;
  const float2* win2 = (const float2*)winT;
  f32x2 wv0, wv1, wv2, wv3;
  { float2 w = win2[mb];       wv0 = f32x2{w.x * Cs, w.y * Cs}; }
  { float2 w = win2[mb + 256]; wv1 = f32x2{w.x * Cs, w.y * Cs}; }
  { float2 w = win2[mb + 512]; wv2 = f32x2{w.x * Cs, w.y * Cs}; }
  { float2 w = win2[mb + 768]; wv3 = f32x2{w.x * Cs, w.y * Cs}; }

  // ---- LDS address constants (swizzled)
  int X0 = PHI(t);
  int B2 = 256 * (t >> 6) + ((t & 63) ^ (((t >> 4) & 3) << 2));
  int b3h = 64 * (t >> 4), i3 = t & 15;
  int b4h = 16 * (t >> 2), i4 = t & 3, c4 = (t >> 2) & 3;
  int p5 = b4h + 4 * ((t & 3) ^ c4);
  int pm0 = PHI((1024 - t) & 1023);
  int pm1 = PHI((1024 - (t + 256)) & 1023);
  int pm2 = PHI((1024 - (t + 512)) & 1023);
  int pm3 = PHI((1024 - (t + 768)) & 1023);

  const float* tftb = tft + (size_t)b * NFR * NCOEF;
  const float2* curb = cur + (size_t)b * 4 * NCOEF;

  int fs = (c == 0) ? 0 : 8 * c - 1;
  int fe = 8 * c + 7;
  int f0 = 8 * c;                       // first stored frame
  f32x2 car0 = f32x2{0.0f, 0.0f}, car1 = f32x2{0.0f, 0.0f};

  // ---- tf prefetch for first pair (fs, fs+1); fs+1 <= fe always
  float ntfA[5], ntfB[5];
  {
    const float* ta = tftb + (size_t)fs * NCOEF;
    const float* tb = tftb + (size_t)(fs + 1) * NCOEF;
#pragma unroll
    for (int i = 0; i < 4; ++i) { ntfA[i] = ta[t + 256 * i]; ntfB[i] = tb[t + 256 * i]; }
    ntfA[4] = (t == 0) ? ta[1024] : 0.0f;
    ntfB[4] = (t == 0) ? tb[1024] : 0.0f;
  }

#define KEEP(x) asm volatile("" : "+v"(x))

  for (int f = fs; f <= fe; f += 2) {
    bool hasB = (f + 1 <= fe);
    KEEP(w1a); KEEP(w2a); KEEP(w3a); KEEP(w4a); KEEP(twp0);

    float ctfA[5], ctfB[5];
#pragma unroll
    for (int i = 0; i < 5; ++i) { ctfA[i] = ntfA[i]; ctfB[i] = ntfB[i]; }

    // ---- issue next pair's tf loads (hidden under this pair's FFTs)
    if (f + 2 <= fe) {
      const float* ta = tftb + (size_t)(f + 2) * NCOEF;
#pragma unroll
      for (int i = 0; i < 4; ++i) ntfA[i] = ta[t + 256 * i];
      ntfA[4] = (t == 0) ? ta[1024] : 0.0f;
      if (f + 3 <= fe) {
        const float* tb = tftb + (size_t)(f + 3) * NCOEF;
#pragma unroll
        for (int i = 0; i < 4; ++i) ntfB[i] = tb[t + 256 * i];
        ntfB[4] = (t == 0) ? tb[1024] : 0.0f;
      }
    }

    // ---- advance recurrence for frame f (A) then f+1 (B), registers
    float sA[5], iA[5], sB[5], iB[5];
#pragma unroll
    for (int i = 0; i < 5; ++i) {
      if (i == 4 && t != 0) { sA[4] = 0.0f; iA[4] = 0.0f; continue; }
      float cr = 0.0f, ci = 0.0f;
      if (f < 4) {
        int k = (i == 4) ? 1024 : t + 256 * i;
        float2 cv = curb[(size_t)f * NCOEF + k];
        cr = cv.x; ci = cv.y;
      }
      float rre = fmaf(pre[i], cgv[i], pim[i] * sgv[i]);
      float rim = -fmaf(pre[i], sgv[i], pim[i] * cgv[i]);
      sA[i] = (cr + rre) * ctfA[i];
      iA[i] = (ci + rim) * ctfA[i];
      pre[i] = sA[i]; pim[i] = iA[i];
    }
    if (hasB) {
#pragma unroll
      for (int i = 0; i < 5; ++i) {
        if (i == 4 && t != 0) { sB[4] = 0.0f; iB[4] = 0.0f; continue; }
        float cr = 0.0f, ci = 0.0f;
        if (f + 1 < 4) {
          int k = (i == 4) ? 1024 : t + 256 * i;
          float2 cv = curb[(size_t)(f + 1) * NCOEF + k];
          cr = cv.x; ci = cv.y;
        }
        float rre = fmaf(pre[i], cgv[i], pim[i] * sgv[i]);
        float rim = -fmaf(pre[i], sgv[i], pim[i] * cgv[i]);
        sB[i] = (cr + rre) * ctfB[i];
        iB[i] = (ci + rim) * ctfB[i];
        pre[i] = sB[i]; pim[i] = iB[i];
      }
    } else {
#pragma unroll
      for (int i = 0; i < 5; ++i) { sB[i] = 0.0f; iB[i] = 0.0f; }
    }

    // ---- X into planes
#pragma unroll
    for (int i = 0; i < 4; ++i) {
      PA[X0 + 256 * i] = f32x2{sA[i], iA[i]};
      PB[X0 + 256 * i] = f32x2{sB[i], iB[i]};
    }
    WGBAR();                               // (alpha) X visible; prev pair retired

    // ---- pack Z + stage-1 butterfly, dual (shared twiddle work)
    const float R2 = 0.70710678118654752f;
    f32x2 twp1 = cmul2(twp0, f32x2{R2, -R2});
    f32x2 twp2 = f32x2{twp0.y, -twp0.x};
    f32x2 twp3 = f32x2{twp1.y, -twp1.x};
    f32x2 w1b = cmul2(w1a, w1a);
    f32x2 w1c = cmul2(w1b, w1a);
    {
      f32x2 twp[4] = {twp0, twp1, twp2, twp3};
      f32x2 ZA[4], ZB[4];
#pragma unroll
      for (int i = 0; i < 4; ++i) {
        int pm = (i == 0) ? pm0 : (i == 1) ? pm1 : (i == 2) ? pm2 : pm3;
        f32x2 tw_c = f32x2{twp[i].x, -twp[i].y};       // e^{+2pi i j/2048}
        {
          f32x2 x = f32x2{sA[i], iA[i]};
          f32x2 xm = (i == 0 && t == 0) ? f32x2{sA[4], 0.0f} : PA[pm];
          f32x2 cjm = f32x2{xm.x, -xm.y};
          f32x2 xe = x + cjm;
          f32x2 xp = x - cjm;
          f32x2 Xo = cmul2(xp, tw_c);
          ZA[i] = f32x2{xe.x - Xo.y, -(xe.y + Xo.x)};
        }
        {
          f32x2 x = f32x2{sB[i], iB[i]};
          f32x2 xm = (i == 0 && t == 0) ? f32x2{sB[4], 0.0f} : PB[pm];
          f32x2 cjm = f32x2{xm.x, -xm.y};
          f32x2 xe = x + cjm;
          f32x2 xp = x - cjm;
          f32x2 Xo = cmul2(xp, tw_c);
          ZB[i] = f32x2{xe.x - Xo.y, -(xe.y + Xo.x)};
        }
      }
      {
        f32x2 A = ZA[0] + ZA[2], B = ZA[0] - ZA[2];
        f32x2 C = ZA[1] + ZA[3], D = ZA[1] - ZA[3];
        f32x2 nD = nid(D);
        QA[X0]       = A + C;
        QA[X0 + 256] = cmul2(B + nD, w1a);
        QA[X0 + 512] = cmul2(A - C, w1b);
        QA[X0 + 768] = cmul2(B - nD, w1c);
      }
      {
        f32x2 A = ZB[0] + ZB[2], B = ZB[0] - ZB[2];
        f32x2 C = ZB[1] + ZB[3], D = ZB[1] - ZB[3];
        f32x2 nD = nid(D);
        QB[X0]       = A + C;
        QB[X0 + 256] = cmul2(B + nD, w1a);
        QB[X0 + 512] = cmul2(A - C, w1b);
        QB[X0 + 768] = cmul2(B - nD, w1c);
      }
    }
    WGBAR();                               // (gamma) y visible across waves

    // ---- stage 2 (wave-local, N=256), dual
    {
      f32x2 w2b = cmul2(w2a, w2a);
      f32x2 w2c = cmul2(w2b, w2a);
      f32x2 a0 = QA[B2], a1 = QA[B2 + 64], a2 = QA[B2 + 128], a3 = QA[B2 + 192];
      f32x2 b0 = QB[B2], b1 = QB[B2 + 64], b2 = QB[B2 + 128], b3 = QB[B2 + 192];
      {
        f32x2 A = a0 + a2, B = a0 - a2, C = a1 + a3, D = a1 - a3;
        f32x2 nD = nid(D);
        QA[B2]       = A + C;
        QA[B2 + 64]  = cmul2(B + nD, w2a);
        QA[B2 + 128] = cmul2(A - C, w2b);
        QA[B2 + 192] = cmul2(B - nD, w2c);
      }
      {
        f32x2 A = b0 + b2, B = b0 - b2, C = b1 + b3, D = b1 - b3;
        f32x2 nD = nid(D);
        QB[B2]       = A + C;
        QB[B2 + 64]  = cmul2(B + nD, w2a);
        QB[B2 + 128] = cmul2(A - C, w2b);
        QB[B2 + 192] = cmul2(B - nD, w2c);
      }
    }
    PIPEFENCE();

    // ---- stage 3 (N=64), dual
    {
      f32x2 w3b = cmul2(w3a, w3a);
      f32x2 w3c = cmul2(w3b, w3a);
      int q0 = b3h + i3, q1 = b3h + 16 + (i3 ^ 4), q2 = b3h + 32 + (i3 ^ 8), q3 = b3h + 48 + (i3 ^ 12);
      f32x2 a0 = QA[q0], a1 = QA[q1], a2 = QA[q2], a3 = QA[q3];
      f32x2 b0 = QB[q0], b1 = QB[q1], b2 = QB[q2], b3 = QB[q3];
      {
        f32x2 A = a0 + a2, B = a0 - a2, C = a1 + a3, D = a1 - a3;
        f32x2 nD = nid(D);
        QA[q0] = A + C;
        QA[q1] = cmul2(B + nD, w3a);
        QA[q2] = cmul2(A - C, w3b);
        QA[q3] = cmul2(B - nD, w3c);
      }
      {
        f32x2 A = b0 + b2, B = b0 - b2, C = b1 + b3, D = b1 - b3;
        f32x2 nD = nid(D);
        QB[q0] = A + C;
        QB[q1] = cmul2(B + nD, w3a);
        QB[q2] = cmul2(A - C, w3b);
        QB[q3] = cmul2(B - nD, w3c);
      }
    }
    PIPEFENCE();

    // ---- stage 4 (N=16), dual
    {
      f32x2 w4b = cmul2(w4a, w4a);
      f32x2 w4c = cmul2(w4b, w4a);
      int q0 = b4h + 4 * (0 ^ c4) + i4, q1 = b4h + 4 * (1 ^ c4) + i4;
      int q2 = b4h + 4 * (2 ^ c4) + i4, q3 = b4h + 4 * (3 ^ c4) + i4;
      f32x2 a0 = QA[q0], a1 = QA[q1], a2 = QA[q2], a3 = QA[q3];
      f32x2 b0 = QB[q0], b1 = QB[q1], b2 = QB[q2], b3 = QB[q3];
      {
        f32x2 A = a0 + a2, B = a0 - a2, C = a1 + a3, D = a1 - a3;
        f32x2 nD = nid(D);
        QA[q0] = A + C;
        QA[q1] = cmul2(B + nD, w4a);
        QA[q2] = cmul2(A - C, w4b);
        QA[q3] = cmul2(B - nD, w4c);
      }
      {
        f32x2 A = b0 + b2, B = b0 - b2, C = b1 + b3, D = b1 - b3;
        f32x2 nD = nid(D);
        QB[q0] = A + C;
        QB[q1] = cmul2(B + nD, w4a);
        QB[q2] = cmul2(A - C, w4b);
        QB[q3] = cmul2(B - nD, w4c);
      }
    }
    PIPEFENCE();

    // ---- stage 5 (N=4) -> regs, dual
    float4 qa01 = *reinterpret_cast<const float4*>(&QA[p5]);
    float4 qa23 = *reinterpret_cast<const float4*>(&QA[p5 + 2]);
    float4 qb01 = *reinterpret_cast<const float4*>(&QB[p5]);
    float4 qb23 = *reinterpret_cast<const float4*>(&QB[p5 + 2]);
    f32x2 zA0, zA1, zA2, zA3, zB0, zB1, zB2, zB3;
    {
      f32x2 a = f32x2{qa01.x, qa01.y}, bq = f32x2{qa01.z, qa01.w};
      f32x2 cq = f32x2{qa23.x, qa23.y}, d = f32x2{qa23.z, qa23.w};
      f32x2 A = a + cq, B = a - cq, C = bq + d, D = bq - d;
      f32x2 nD = nid(D);
      zA0 = A + C; zA1 = B + nD; zA2 = A - C; zA3 = B - nD;
    }
    {
      f32x2 a = f32x2{qb01.x, qb01.y}, bq = f32x2{qb01.z, qb01.w};
      f32x2 cq = f32x2{qb23.x, qb23.y}, d = f32x2{qb23.z, qb23.w};
      f32x2 A = a + cq, B = a - cq, C = bq + d, D = bq - d;
      f32x2 nD = nid(D);
      zB0 = A + C; zB1 = B + nD; zB2 = A - C; zB3 = B - nD;
    }

    // ---- extract A then B with register carry
    {
      f32x2 e0 = f32x2{zA0.x, -zA0.y} * wv0;
      f32x2 e1 = f32x2{zA1.x, -zA1.y} * wv1;
      f32x2 e2 = f32x2{zA2.x, -zA2.y} * wv2;
      f32x2 e3 = f32x2{zA3.x, -zA3.y} * wv3;
      if (f >= f0) {
        f32x2* ob2 = (f32x2*)(out + (size_t)b * NSAMP + (size_t)f * 1024);
        ob2[mb]       = e0 + car0;
        ob2[mb + 256] = e1 + car1;
      }
      car0 = e2;
      car1 = e3;
    }
    if (hasB) {
      f32x2 e0 = f32x2{zB0.x, -zB0.y} * wv0;
      f32x2 e1 = f32x2{zB1.x, -zB1.y} * wv1;
      f32x2 e2 = f32x2{zB2.x, -zB2.y} * wv2;
      f32x2 e3 = f32x2{zB3.x, -zB3.y} * wv3;
      f32x2* ob2 = (f32x2*)(out + (size_t)b * NSAMP + (size_t)(f + 1) * 1024);
      ob2[mb]       = e0 + car0;
      ob2[mb + 256] = e1 + car1;
      car0 = e2;
      car1 = e3;
    }
  }
#undef KEEP
}

// ---------------------------------------------------------------- launch
extern "C" void kernel_launch(void* const* d_in, const int* in_sizes, int n_in,
                              void* d_out, int out_size, void* d_ws, size_t ws_size,
                              hipStream_t stream) {
  const float* z    = (const float*)d_in[0];
  const float* imp  = (const float*)d_in[1];
  const float* W    = (const float*)d_in[2];
  const float* bias = (const float*)d_in[3];

  float* ws = (float*)d_ws;
  float*  tf   = ws + TF_OFF;
  float*  tft  = ws + TFT_OFF;
  float2* cur  = (float2*)(ws + CUR_OFF);
  float2* ckp  = (float2*)(ws + CK_OFF);
  float*  winT = ws + WINT_OFF;
  float2* twG  = (float2*)(ws + TW_OFF);
  short*  zbf  = (short*)(ws + ZBF_OFF);
  float*  out  = (float*)d_out;

  init_tables<<<32, 256, 0, stream>>>(z, winT, twG, zbf);
  tf_gemm_mfma<<<COLS / 32, 256, 0, stream>>>(zbf, W, bias, tf);
  fwd_fft_kernel<<<NB * 4, 256, 0, stream>>>(imp, winT, twG, cur);
  recur_ck_t<<<(NB * NCOEF + 255) / 256, 256, 0, stream>>>(tf, cur, ckp, tft);
  fused_resyn<<<NB * NCHUNK, 256, 0, stream>>>(tft, cur, ckp, winT, twG, out);
}

// Round 20
// 85.324 us; speedup vs baseline: 1.0213x; 1.0213x over previous
//
#include <hip/hip_runtime.h>

#define NB 64
#define ZDIM 128
#define NCOEF 1025
#define NFR 128
#define COLS 131200          /* NCOEF*NFR */
#define WINSZ 2048
#define HALFW 1024
#define NSAMP 131072
#define IMPN 4096
#define NCHUNK 32            /* chunks of 4 spans */
#define NCK 31               /* checkpoints after frames 2,6,...,122 */

// workspace layout in floats
#define TF_OFF   0
#define TF_SZ    (NB*COLS)
#define TFT_OFF  (TF_OFF + TF_SZ)
#define TFT_SZ   (NB*NFR*NCOEF)
#define CUR_OFF  (TFT_OFF + TFT_SZ)
#define CUR_SZ   (NB*4*NCOEF*2)
#define CK_OFF   (CUR_OFF + CUR_SZ)
#define CK_SZ    (NCK*NB*NCOEF*2)
#define WINT_OFF (CK_OFF + CK_SZ)
#define WINT_SZ  (WINSZ)
#define TW_OFF   (WINT_OFF + WINT_SZ)
#define TW_SZ    (HALFW*2)
#define ZBF_OFF  (TW_OFF + TW_SZ)
#define ZBF_SZ   (NB*ZDIM/2)

// 2-bit XOR swizzle for the FFT plane: bits[3:2] ^= bits[5:4]
#define PHI(p) ((p) ^ ((((p) >> 4) & 3) << 2))

typedef short bf16x8 __attribute__((ext_vector_type(8)));
typedef float f32x4 __attribute__((ext_vector_type(4)));
typedef float f32x2 __attribute__((ext_vector_type(2)));

// packed complex multiply: 1 pk_mul + 1 pk_fma (fp-contract)
__device__ __forceinline__ f32x2 cmul2(f32x2 a, f32x2 b) {
  f32x2 t = f32x2{a.x, a.x} * b;
  return f32x2{-a.y, a.y} * f32x2{b.y, b.x} + t;
}
// multiply by -i
__device__ __forceinline__ f32x2 nid(f32x2 d) { return f32x2{d.y, -d.x}; }

// full LDS drain + barrier (cross-wave visibility)
#define WGBAR()                                              \
  do {                                                       \
    asm volatile("s_waitcnt lgkmcnt(0)" ::: "memory");       \
    __builtin_amdgcn_s_barrier();                            \
    asm volatile("" ::: "memory");                           \
  } while (0)

// compiler-only fence for wave-local stage boundaries (validated round 17)
#define PIPEFENCE() asm volatile("" ::: "memory")

__device__ __forceinline__ short f2bf(float f) {
  unsigned u = __builtin_bit_cast(unsigned, f);
  u += 0x7FFFu + ((u >> 16) & 1u);      // RNE
  return (short)(u >> 16);
}

__device__ __forceinline__ void gload_lds16(const float* g, float* l) {
  __builtin_amdgcn_global_load_lds(
      (const __attribute__((address_space(1))) unsigned int*)(const void*)g,
      (__attribute__((address_space(3))) unsigned int*)(void*)l, 16, 0, 0);
}

// ---------------------------------------------------------------- init tables (+ z->bf16)
__global__ __launch_bounds__(256) void init_tables(const float* __restrict__ z,
                                                   float* __restrict__ winT,
                                                   float2* __restrict__ twG,
                                                   short* __restrict__ zbf) {
  int i = blockIdx.x * 256 + threadIdx.x;   // grid 32*256 = 8192
  if (i < WINSZ) {
    winT[i] = 0.5f - 0.5f * cosf((float)(2.0 * 3.14159265358979323846 / 2048.0) * (float)i);
  }
  if (i < HALFW) {
    float ang = (float)(-2.0 * 3.14159265358979323846 / 2048.0) * (float)i;
    float sv, cv;
    sincosf(ang, &sv, &cv);
    twG[i] = make_float2(cv, sv);
  }
  if (i < NB * ZDIM) zbf[i] = f2bf(z[i]);
}

// ---------------------------------------------------------------- MFMA GEMM + squash
// 32-col tiles (grid 4100): W tile 128x32 f32 = 16KB LDS -> deep cross-block
// fetch overlap. Wave w owns rows 16w..16w+15.
__global__ __launch_bounds__(256) void tf_gemm_mfma(const short* __restrict__ zbf,
                                                    const float* __restrict__ W,
                                                    const float* __restrict__ bias,
                                                    float* __restrict__ tf) {
  __shared__ float Wt[128 * 32];   // [k][col], 16 KB
  int tid = threadIdx.x;
  int wave = tid >> 6, lane = tid & 63;
  int colb = blockIdx.x * 32;

#pragma unroll
  for (int it = 0; it < 4; ++it) {
    int ci = tid + it * 256;
    const float* src = W + (size_t)(ci >> 3) * COLS + colb + (ci & 7) * 4;
    gload_lds16(src, &Wt[ci * 4]);
  }

  int lr = lane & 15;
  int lk = (lane >> 4) * 8;
  int lq = (lane >> 4) * 4;

  float bv[2];
#pragma unroll
  for (int n = 0; n < 2; ++n) bv[n] = bias[colb + 16 * n + lr];

  f32x4 acc[2];
#pragma unroll
  for (int n = 0; n < 2; ++n)
    acc[n] = f32x4{bv[n], bv[n], bv[n], bv[n]};

  bf16x8 afr[4];
#pragma unroll
  for (int s = 0; s < 4; ++s)
    afr[s] = *reinterpret_cast<const bf16x8*>(zbf + (16 * wave + lr) * ZDIM + s * 32 + lk);

  __syncthreads();   // stage complete

#pragma unroll
  for (int s = 0; s < 4; ++s) {
    bf16x8 bfr[2];
#pragma unroll
    for (int n = 0; n < 2; ++n) {
      const float* wp = &Wt[(s * 32 + lk) * 32 + 16 * n + lr];
      bfr[n] = bf16x8{f2bf(wp[0 * 32]), f2bf(wp[1 * 32]), f2bf(wp[2 * 32]), f2bf(wp[3 * 32]),
                      f2bf(wp[4 * 32]), f2bf(wp[5 * 32]), f2bf(wp[6 * 32]), f2bf(wp[7 * 32])};
    }
#pragma unroll
    for (int n = 0; n < 2; ++n)
      acc[n] = __builtin_amdgcn_mfma_f32_16x16x32_bf16(afr[s], bfr[n], acc[n], 0, 0, 0);
  }

  const float RESR = (1.0f - 0.02f) * 0.99f;
#pragma unroll
  for (int n = 0; n < 2; ++n) {
    int col = colb + 16 * n + lr;
#pragma unroll
    for (int r = 0; r < 4; ++r) {
      int row = 16 * wave + lq + r;
      float x = acc[n][r];
      float sg = 1.0f / (1.0f + __expf(-x));
      tf[(size_t)row * COLS + col] = 0.02f + sg * RESR;
    }
  }
}

// ---------------------------------------------------------------- fwd 2048 FFT (radix-2)
static __device__ __forceinline__ void wg_fft2048(float* ar, float* ai,
                                                  float* br, float* bi,
                                                  const float2* tw,
                                                  float** outr, float** outi) {
  float *xr = ar, *xi = ai, *yr = br, *yi = bi;
  int m = 1;
  for (int s = 0; s < 11; ++s) {
    __syncthreads();
#pragma unroll
    for (int it = 0; it < 4; ++it) {
      int t = (int)threadIdx.x + it * 256;
      int jm = t & ~(m - 1);
      float x0r = xr[t], x0i = xi[t];
      float x1r = xr[t + 1024], x1i = xi[t + 1024];
      float2 w = tw[jm];
      float sr = x0r + x1r, si = x0i + x1i;
      float dr = x0r - x1r, di = x0i - x1i;
      float pr = dr * w.x - di * w.y;
      float pi = dr * w.y + di * w.x;
      yr[t + jm] = sr;      yi[t + jm] = si;
      yr[t + jm + m] = pr;  yi[t + jm + m] = pi;
    }
    float* t0 = xr; xr = yr; yr = t0;
    float* t1 = xi; xi = yi; yi = t1;
    m <<= 1;
  }
  __syncthreads();
  *outr = xr; *outi = xi;
}

__global__ __launch_bounds__(256) void fwd_fft_kernel(const float* __restrict__ imp,
                                                      const float* __restrict__ winT,
                                                      const float2* __restrict__ twG,
                                                      float2* __restrict__ cur) {
  __shared__ float b0r[WINSZ], b0i[WINSZ], b1r[WINSZ], b1i[WINSZ];
  __shared__ float2 tw[HALFW];
  int wg = blockIdx.x;
  int b = wg >> 2, f = wg & 3;
  int tid = threadIdx.x;

  for (int i = tid; i < HALFW; i += 256) tw[i] = twG[i];
  for (int w = tid; w < WINSZ; w += 256) {
    int s = f * HALFW + w;
    float v = (s < IMPN) ? imp[(size_t)b * IMPN + s] * winT[w] : 0.0f;
    b0r[w] = v;
    b0i[w] = 0.0f;
  }
  float *rr, *ri;
  wg_fft2048(b0r, b0i, b1r, b1i, tw, &rr, &ri);
  for (int k = tid; k < NCOEF; k += 256)
    cur[(size_t)wg * NCOEF + k] = make_float2(rr[k], ri[k]);
}

// ---------------------------------------------------------------- recurrence checkpoints + tf transpose
__global__ __launch_bounds__(256) void recur_ck_t(const float* __restrict__ tf,
                                                  const float2* __restrict__ cur,
                                                  float2* __restrict__ ckp,
                                                  float* __restrict__ tft) {
  int id = blockIdx.x * 256 + threadIdx.x;
  if (id >= NB * NCOEF) return;
  int b = id / NCOEF;
  int k = id - b * NCOEF;

  float g = 3.14159265358979323846f * (float)k / 1024.0f;
  float sg, cg;
  sincosf(g, &sg, &cg);
  bool herm = (k == 0) || (k == HALFW);

  const float4* tf4 = (const float4*)(tf + (size_t)b * COLS + (size_t)k * NFR);
  const float2* curb = cur + (size_t)b * 4 * NCOEF + k;
  float* tftb = tft + (size_t)b * NFR * NCOEF + k;

  float pre = 0.0f, pim = 0.0f;
  for (int f4 = 0; f4 < 32; ++f4) {
    float4 tv = tf4[f4];
    float tfs[4] = {tv.x, tv.y, tv.z, tv.w};
#pragma unroll
    for (int u = 0; u < 4; ++u) {
      int f = 4 * f4 + u;
      tftb[(size_t)f * NCOEF] = tfs[u];       // coalesced transpose write
      if (f < 124) {
        float tfv = tfs[u];
        float cr = 0.0f, ci = 0.0f;
        if (f < 4) {
          float2 cv = curb[(size_t)f * NCOEF];
          cr = cv.x; ci = cv.y;
        }
        float ire = herm ? 0.0f : pim;
        float rre = fmaf(pre, cg, ire * sg);
        float rim = -fmaf(pre, sg, ire * cg);
        float sre = (cr + rre) * tfv;
        float sim = (ci + rim) * tfv;
        if ((f & 3) == 2)
          ckp[(size_t)((f - 2) >> 2) * NB * NCOEF + (size_t)b * NCOEF + k] = make_float2(sre, sim);
        pre = sre; pim = sim;
      }
    }
  }
}

// ---------------------------------------------------------------- fused recur + irfft + OLA
// Register DIF radix-4; P/Q planes; 2 LDS barriers/frame (beta removed:
// alpha's lgkmcnt(0)+barrier already retires all waves' prev stage-5 Q-reads).
// Wave-local stages ordered by compiler fences (in-order per-wave DS pipe).
__global__ __launch_bounds__(256) void fused_resyn(const float* __restrict__ tft,
                                                   const float2* __restrict__ cur,
                                                   const float2* __restrict__ ckp,
                                                   const float* __restrict__ winT,
                                                   const float2* __restrict__ twG,
                                                   float* __restrict__ out) {
  __shared__ f32x2 P[1024];   // X plane (mirror source)
  __shared__ f32x2 Q[1024];   // butterfly work plane

  int bidx = blockIdx.x;
  int b = bidx >> 5, c = bidx & 31;
  int t = threadIdx.x;

  // ---- recurrence slots: k = t + 256*i (i<4); thread 0 also owns k=1024
  float pre[5], pim[5], cgv[5], sgv[5];
#pragma unroll
  for (int i = 0; i < 5; ++i) {
    if (i == 4) { cgv[4] = -1.0f; sgv[4] = 0.0f; }
    else {
      float2 tv = twG[t + 256 * i];
      cgv[i] = tv.x; sgv[i] = -tv.y;       // cos/sin(pi*k/1024)
    }
    pre[i] = 0.0f; pim[i] = 0.0f;
  }
  if (c > 0) {
    const float2* ck = ckp + ((size_t)(c - 1) * NB + b) * NCOEF;
#pragma unroll
    for (int i = 0; i < 5; ++i) {
      if (i == 4 && t != 0) continue;
      int k = (i == 4) ? 1024 : t + 256 * i;
      float2 v = ck[k];
      pre[i] = v.x; pim[i] = v.y;
    }
  }

  // ---- base twiddles only (squares/cubes recomputed per frame, packed)
  float2 tl;
  tl = twG[2 * t];          f32x2 w1a = f32x2{tl.x, tl.y};
  tl = twG[8 * (t & 63)];   f32x2 w2a = f32x2{tl.x, tl.y};
  tl = twG[32 * (t & 15)];  f32x2 w3a = f32x2{tl.x, tl.y};
  tl = twG[128 * (t & 3)];  f32x2 w4a = f32x2{tl.x, tl.y};
  tl = twG[t];              f32x2 twp0 = f32x2{tl.x, tl.y};

  // ---- extract constants (digit-reversed positions); 1/2048 scale folded in
  const float Cs = 0.5f / 1024.0f;
  int mb = (t >> 6) + ((t >> 4) & 3) * 4 + ((t >> 2) & 3) * 16 + (t & 3) * 64;
  const float2* win2 = (const float2*)winT;
  f32x2 wv0, wv1, wv2, wv3;
  { float2 w = win2[mb];       wv0 = f32x2{w.x * Cs, w.y * Cs}; }
  { float2 w = win2[mb + 256]; wv1 = f32x2{w.x * Cs, w.y * Cs}; }
  { float2 w = win2[mb + 512]; wv2 = f32x2{w.x * Cs, w.y * Cs}; }
  { float2 w = win2[mb + 768]; wv3 = f32x2{w.x * Cs, w.y * Cs}; }

  // ---- LDS address constants (swizzled)
  int X0 = PHI(t);
  int B2 = 256 * (t >> 6) + ((t & 63) ^ (((t >> 4) & 3) << 2));
  int b3h = 64 * (t >> 4), i3 = t & 15;
  int b4h = 16 * (t >> 2), i4 = t & 3, c4 = (t >> 2) & 3;
  int p5 = b4h + 4 * ((t & 3) ^ c4);
  int pm0 = PHI((1024 - t) & 1023);
  int pm1 = PHI((1024 - (t + 256)) & 1023);
  int pm2 = PHI((1024 - (t + 512)) & 1023);
  int pm3 = PHI((1024 - (t + 768)) & 1023);

  const float* tftb = tft + (size_t)b * NFR * NCOEF;
  const float2* curb = cur + (size_t)b * 4 * NCOEF;

  int fs = (c == 0) ? 0 : 4 * c - 1;
  int fe = 4 * c + 3;
  f32x2 car0 = f32x2{0.0f, 0.0f}, car1 = f32x2{0.0f, 0.0f};

  // ---- tf prefetch for frame fs
  float ntf[5];
  {
    const float* tfr = tftb + (size_t)fs * NCOEF;
#pragma unroll
    for (int i = 0; i < 4; ++i) ntf[i] = tfr[t + 256 * i];
    ntf[4] = (t == 0) ? tfr[1024] : 0.0f;
  }

#define KEEP(x) asm volatile("" : "+v"(x))

  for (int f = fs; f <= fe; ++f) {
    // tie base twiddles so derived powers are recomputed (not hoisted)
    KEEP(w1a); KEEP(w2a); KEEP(w3a); KEEP(w4a); KEEP(twp0);

    float ctf[5];
#pragma unroll
    for (int i = 0; i < 5; ++i) ctf[i] = ntf[i];

    // ---- issue next frame's tf loads (hide under this frame's FFT)
    if (f < fe) {
      const float* tfr = tftb + (size_t)(f + 1) * NCOEF;
#pragma unroll
      for (int i = 0; i < 4; ++i) ntf[i] = tfr[t + 256 * i];
      ntf[4] = (t == 0) ? tfr[1024] : 0.0f;
    }

    // ---- advance recurrence (registers)
    float S[5], I[5];
#pragma unroll
    for (int i = 0; i < 5; ++i) {
      if (i == 4 && t != 0) { S[4] = 0.0f; I[4] = 0.0f; continue; }
      float cr = 0.0f, ci = 0.0f;
      if (f < 4) {
        int k = (i == 4) ? 1024 : t + 256 * i;
        float2 cv = curb[(size_t)f * NCOEF + k];
        cr = cv.x; ci = cv.y;
      }
      float rre = fmaf(pre[i], cgv[i], pim[i] * sgv[i]);
      float rim = -fmaf(pre[i], sgv[i], pim[i] * cgv[i]);
      S[i] = (cr + rre) * ctf[i];
      I[i] = (ci + rim) * ctf[i];
      pre[i] = S[i]; pim[i] = I[i];
    }

    // ---- X into P
#pragma unroll
    for (int i = 0; i < 4; ++i)
      P[X0 + 256 * i] = f32x2{S[i], I[i]};
    WGBAR();                               // (alpha) X visible; prev frame fully retired

    // ---- pack Z (own X from regs; mirror from P) + stage-1 butterfly (packed)
    const float R2 = 0.70710678118654752f;
    f32x2 twp1 = cmul2(twp0, f32x2{R2, -R2});
    f32x2 twp2 = f32x2{twp0.y, -twp0.x};
    f32x2 twp3 = f32x2{twp1.y, -twp1.x};
    f32x2 Z[4];
    {
      f32x2 xm[4];
      xm[0] = (t == 0) ? f32x2{S[4], 0.0f} : P[pm0];
      xm[1] = P[pm1]; xm[2] = P[pm2]; xm[3] = P[pm3];
      f32x2 twp[4] = {twp0, twp1, twp2, twp3};
#pragma unroll
      for (int i = 0; i < 4; ++i) {
        f32x2 x = f32x2{S[i], I[i]};
        f32x2 cjm = f32x2{xm[i].x, -xm[i].y};        // conj(mirror)
        f32x2 xe = x + cjm;
        f32x2 xp = x - cjm;
        f32x2 Xo = cmul2(xp, f32x2{twp[i].x, -twp[i].y});   // * e^{+2pi i j/2048}
        Z[i] = f32x2{xe.x - Xo.y, -(xe.y + Xo.x)};
      }
    }
    {
      f32x2 w1b = cmul2(w1a, w1a);
      f32x2 w1c = cmul2(w1b, w1a);
      f32x2 A = Z[0] + Z[2];
      f32x2 B = Z[0] - Z[2];
      f32x2 C = Z[1] + Z[3];
      f32x2 D = Z[1] - Z[3];
      f32x2 nD = nid(D);
      Q[X0]       = A + C;
      Q[X0 + 256] = cmul2(B + nD, w1a);
      Q[X0 + 512] = cmul2(A - C, w1b);
      Q[X0 + 768] = cmul2(B - nD, w1c);
    }
    WGBAR();                               // (gamma) y visible across waves

    // ---- stage 2 (wave-local, N=256)
    {
      f32x2 u0 = Q[B2], u1 = Q[B2 + 64], u2 = Q[B2 + 128], u3 = Q[B2 + 192];
      f32x2 w2b = cmul2(w2a, w2a);
      f32x2 w2c = cmul2(w2b, w2a);
      f32x2 A = u0 + u2, B = u0 - u2, C = u1 + u3, D = u1 - u3;
      f32x2 nD = nid(D);
      Q[B2]       = A + C;
      Q[B2 + 64]  = cmul2(B + nD, w2a);
      Q[B2 + 128] = cmul2(A - C, w2b);
      Q[B2 + 192] = cmul2(B - nD, w2c);
    }
    PIPEFENCE();

    // ---- stage 3 (N=64)
    {
      f32x2 u0 = Q[b3h + i3];
      f32x2 u1 = Q[b3h + 16 + (i3 ^ 4)];
      f32x2 u2 = Q[b3h + 32 + (i3 ^ 8)];
      f32x2 u3 = Q[b3h + 48 + (i3 ^ 12)];
      f32x2 w3b = cmul2(w3a, w3a);
      f32x2 w3c = cmul2(w3b, w3a);
      f32x2 A = u0 + u2, B = u0 - u2, C = u1 + u3, D = u1 - u3;
      f32x2 nD = nid(D);
      Q[b3h + i3]             = A + C;
      Q[b3h + 16 + (i3 ^ 4)]  = cmul2(B + nD, w3a);
      Q[b3h + 32 + (i3 ^ 8)]  = cmul2(A - C, w3b);
      Q[b3h + 48 + (i3 ^ 12)] = cmul2(B - nD, w3c);
    }
    PIPEFENCE();

    // ---- stage 4 (N=16)
    {
      f32x2 u0 = Q[b4h + 4 * (0 ^ c4) + i4];
      f32x2 u1 = Q[b4h + 4 * (1 ^ c4) + i4];
      f32x2 u2 = Q[b4h + 4 * (2 ^ c4) + i4];
      f32x2 u3 = Q[b4h + 4 * (3 ^ c4) + i4];
      f32x2 w4b = cmul2(w4a, w4a);
      f32x2 w4c = cmul2(w4b, w4a);
      f32x2 A = u0 + u2, B = u0 - u2, C = u1 + u3, D = u1 - u3;
      f32x2 nD = nid(D);
      Q[b4h + 4 * (0 ^ c4) + i4] = A + C;
      Q[b4h + 4 * (1 ^ c4) + i4] = cmul2(B + nD, w4a);
      Q[b4h + 4 * (2 ^ c4) + i4] = cmul2(A - C, w4b);
      Q[b4h + 4 * (3 ^ c4) + i4] = cmul2(B - nD, w4c);
    }
    PIPEFENCE();

    // ---- stage 5 (N=4, no twiddles) -> regs
    float4 q01 = *reinterpret_cast<const float4*>(&Q[p5]);
    float4 q23 = *reinterpret_cast<const float4*>(&Q[p5 + 2]);
    f32x2 z0, z1, z2, z3;
    {
      f32x2 a = f32x2{q01.x, q01.y}, bq = f32x2{q01.z, q01.w};
      f32x2 cq = f32x2{q23.x, q23.y}, d = f32x2{q23.z, q23.w};
      f32x2 A = a + cq, B = a - cq, C = bq + d, D = bq - d;
      f32x2 nD = nid(D);
      z0 = A + C;
      z1 = B + nD;
      z2 = A - C;
      z3 = B - nD;
    }

    // ---- extract: x[2m]=Re z[m]*wv.x, x[2m+1]=-Im z[m]*wv.y; m = mb + 256q
    f32x2 e0 = f32x2{z0.x, -z0.y} * wv0;
    f32x2 e1 = f32x2{z1.x, -z1.y} * wv1;
    f32x2 e2 = f32x2{z2.x, -z2.y} * wv2;
    f32x2 e3 = f32x2{z3.x, -z3.y} * wv3;
    if (f >= 4 * c) {
      f32x2* ob2 = (f32x2*)(out + (size_t)b * NSAMP + (size_t)f * 1024);
      ob2[mb]       = e0 + car0;
      ob2[mb + 256] = e1 + car1;
    }
    car0 = e2;
    car1 = e3;
  }
#undef KEEP
}

// ---------------------------------------------------------------- launch
extern "C" void kernel_launch(void* const* d_in, const int* in_sizes, int n_in,
                              void* d_out, int out_size, void* d_ws, size_t ws_size,
                              hipStream_t stream) {
  const float* z    = (const float*)d_in[0];
  const float* imp  = (const float*)d_in[1];
  const float* W    = (const float*)d_in[2];
  const float* bias = (const float*)d_in[3];

  float* ws = (float*)d_ws;
  float*  tf   = ws + TF_OFF;
  float*  tft  = ws + TFT_OFF;
  float2* cur  = (float2*)(ws + CUR_OFF);
  float2* ckp  = (float2*)(ws + CK_OFF);
  float*  winT = ws + WINT_OFF;
  float2* twG  = (float2*)(ws + TW_OFF);
  short*  zbf  = (short*)(ws + ZBF_OFF);
  float*  out  = (float*)d_out;

  init_tables<<<32, 256, 0, stream>>>(z, winT, twG, zbf);
  tf_gemm_mfma<<<COLS / 32, 256, 0, stream>>>(zbf, W, bias, tf);
  fwd_fft_kernel<<<NB * 4, 256, 0, stream>>>(imp, winT, twG, cur);
  recur_ck_t<<<(NB * NCOEF + 255) / 256, 256, 0, stream>>>(tf, cur, ckp, tft);
  fused_resyn<<<NB * NCHUNK, 256, 0, stream>>>(tft, cur, ckp, winT, twG, out);
}